// Round 1
// baseline (1404.694 us; speedup 1.0000x reference)
//
#include <hip/hip_runtime.h>

typedef __attribute__((ext_vector_type(4))) float floatx4;
typedef __attribute__((ext_vector_type(8))) short shortx8;

#define AS1 __attribute__((address_space(1)))
#define AS3 __attribute__((address_space(3)))

constexpr int Tt = 4096;       // tokens (2*2048)
constexpr int Dm = 1024;       // d_model
constexpr int Hd = 4096;       // hidden
constexpr int ROWS_CAP = 13312; // 104 tiles * 128: 8192 routed + pad + 4096 shared
constexpr int NT_CAP = 104;
constexpr int YN = Tt * Dm;

// ---------- helpers ----------
__device__ __forceinline__ unsigned short f2bf(float f) {
  unsigned u = __builtin_bit_cast(unsigned, f);
  u = (u + 0x7fffu + ((u >> 16) & 1u)) >> 16;  // round-to-nearest-even
  return (unsigned short)u;
}

__device__ __forceinline__ void load_lds16(const unsigned short* g, unsigned short* l) {
  __builtin_amdgcn_global_load_lds((const AS1 unsigned int*)g, (AS3 unsigned int*)l, 16, 0, 0);
}

// ---------- cast + transpose fp32 [R][C] -> bf16 [C][R], batched over z ----------
__global__ void tcast(const float* __restrict__ in, unsigned short* __restrict__ out,
                      int R, int C) {
  __shared__ float tile[32][33];
  size_t mat = blockIdx.z;
  const float* ip = in + mat * (size_t)R * C;
  unsigned short* op = out + mat * (size_t)R * C;
  int c0 = blockIdx.x * 32, r0 = blockIdx.y * 32;
  int tx = threadIdx.x, ty = threadIdx.y;  // block (32,8)
#pragma unroll
  for (int i = ty; i < 32; i += 8)
    tile[i][tx] = ip[(size_t)(r0 + i) * C + (c0 + tx)];
  __syncthreads();
#pragma unroll
  for (int i = ty; i < 32; i += 8)
    op[(size_t)(c0 + i) * R + (r0 + tx)] = f2bf(tile[tx][i]);
}

// ---------- router: fp32 exact; 1 wave per token ----------
__global__ void router_kernel(const float* __restrict__ x, const float* __restrict__ wr,
                              int* __restrict__ tok_exp, float* __restrict__ tok_w,
                              int* __restrict__ counts, double* __restrict__ psum) {
  int wave = threadIdx.x >> 6, lane = threadIdx.x & 63;
  int t = blockIdx.x * 4 + wave;
  const float* xp = x + (size_t)t * Dm;
  float xi[16];
#pragma unroll
  for (int j = 0; j < 16; j++) xi[j] = xp[lane + j * 64];
  float sc[8];
#pragma unroll
  for (int e = 0; e < 8; e++) {
    const float* wp = wr + e * Dm;
    float acc = 0.f;
#pragma unroll
    for (int j = 0; j < 16; j++) acc += xi[j] * wp[lane + j * 64];
#pragma unroll
    for (int s = 32; s; s >>= 1) acc += __shfl_xor(acc, s, 64);
    sc[e] = acc;
  }
  // softmax (all lanes redundantly)
  float m = sc[0];
#pragma unroll
  for (int e = 1; e < 8; e++) m = fmaxf(m, sc[e]);
  float sum = 0.f;
#pragma unroll
  for (int e = 0; e < 8; e++) { sc[e] = __expf(sc[e] - m); sum += sc[e]; }
  float inv = 1.0f / sum;
#pragma unroll
  for (int e = 0; e < 8; e++) sc[e] *= inv;
  // group scores: G=4 groups of 2; keep top-2 groups (lowest index wins ties)
  float gs[4];
#pragma unroll
  for (int g = 0; g < 4; g++) gs[g] = fmaxf(sc[2 * g], sc[2 * g + 1]);
  int g1 = -1, g2 = -1; float b1 = -1e30f, b2 = -1e30f;
#pragma unroll
  for (int g = 0; g < 4; g++) if (gs[g] > b1) { b1 = gs[g]; g1 = g; }
#pragma unroll
  for (int g = 0; g < 4; g++) if (g != g1 && gs[g] > b2) { b2 = gs[g]; g2 = g; }
  // top-2 experts among kept groups
  int e1 = -1, e2 = -1; float c1 = -1e30f, c2 = -1e30f;
#pragma unroll
  for (int e = 0; e < 8; e++) {
    int g = e >> 1; bool keep = (g == g1) || (g == g2);
    if (keep && sc[e] > c1) { c1 = sc[e]; e1 = e; }
  }
#pragma unroll
  for (int e = 0; e < 8; e++) {
    int g = e >> 1; bool keep = (g == g1) || (g == g2);
    if (keep && e != e1 && sc[e] > c2) { c2 = sc[e]; e2 = e; }
  }
  if (lane == 0) {
    tok_exp[t * 2] = e1; tok_w[t * 2] = c1;
    tok_exp[t * 2 + 1] = e2; tok_w[t * 2 + 1] = c2;
    atomicAdd(&counts[e1], 1);
    atomicAdd(&counts[e2], 1);
  }
  float mysc = 0.f;
#pragma unroll
  for (int e = 0; e < 8; e++) if (e == lane) mysc = sc[e];
  if (lane < 8) atomicAdd(&psum[lane], (double)mysc);
}

// ---------- offsets + tile->expert map (serial, tiny) ----------
__global__ void make_offsets(const int* __restrict__ counts, int* __restrict__ off,
                             int* __restrict__ tile_e) {
  if (threadIdx.x == 0) {
    int o[10];
    o[0] = 0;
    for (int e = 0; e < 8; e++) o[e + 1] = o[e] + ((counts[e] + 127) & ~127);
    o[9] = o[8] + Tt;  // shared-expert segment (expert id 8), exactly Tt rows
    for (int e = 0; e < 10; e++) off[e] = o[e];
    int nt = o[9] >> 7;
    for (int i = 0; i < NT_CAP; i++) {
      int te = -1;
      if (i < nt) {
        int r = i << 7;
        for (int e = 0; e < 9; e++)
          if (r >= o[e] && r < o[e + 1]) te = e;
      }
      tile_e[i] = te;
    }
  }
}

// ---------- gather token rows (bf16) into padded per-expert segments ----------
__global__ void gather_kernel(const float* __restrict__ x, const int* __restrict__ tok_exp,
                              const float* __restrict__ tok_w, const int* __restrict__ off,
                              int* __restrict__ fill, int* __restrict__ rows,
                              float* __restrict__ rw, unsigned short* __restrict__ xg) {
  int t = blockIdx.x;
  int tid = threadIdx.x;
  __shared__ int spos[3];
  if (tid < 2) {
    int e = tok_exp[t * 2 + tid];
    int p = off[e] + atomicAdd(&fill[e], 1);
    spos[tid] = p; rows[p] = t; rw[p] = tok_w[t * 2 + tid];
  } else if (tid == 2) {
    int p = off[8] + t;
    spos[2] = p; rows[p] = t; rw[p] = 1.0f;
  }
  __syncthreads();
  float4 v = ((const float4*)(x + (size_t)t * Dm))[tid];  // 256 threads * float4 = 1024
  ushort4 b;
  b.x = f2bf(v.x); b.y = f2bf(v.y); b.z = f2bf(v.z); b.w = f2bf(v.w);
#pragma unroll
  for (int k = 0; k < 3; k++)
    ((ushort4*)(xg + (size_t)spos[k] * Dm))[tid] = b;
}

// ---------- GEMM1: h = (Xg @ Wfc) * silu(Xg @ Wgate), bf16 out ----------
// 128x128 tile, BK=64, 4 waves (2x2 of 64x64), mfma 16x16x32 bf16.
__global__ __launch_bounds__(256) void gemm_fcgate(
    const unsigned short* __restrict__ xg,   // [ROWS_CAP][Dm]
    const unsigned short* __restrict__ wfc,  // [9][Hd][Dm]  (transposed: row=n, col=k)
    const unsigned short* __restrict__ wgt,  // [9][Hd][Dm]
    const int* __restrict__ tile_e,
    unsigned short* __restrict__ hg)         // [ROWS_CAP][Hd]
{
  int rt = blockIdx.y;
  int e = tile_e[rt];
  if (e < 0) return;
  int n0 = blockIdx.x * 128;
  __shared__ __align__(16) unsigned short lds[3 * 128 * 64];
  unsigned short* a_s = lds;
  unsigned short* bf_s = lds + 128 * 64;
  unsigned short* bg_s = lds + 2 * 128 * 64;
  int tid = threadIdx.x;
  int wave = tid >> 6, lane = tid & 63;
  int quad = lane >> 4, l15 = lane & 15;
  const unsigned short* Ab = xg + (size_t)rt * 128 * Dm;
  const unsigned short* Bf = wfc + (size_t)e * Hd * Dm + (size_t)n0 * Dm;
  const unsigned short* Bg = wgt + (size_t)e * Hd * Dm + (size_t)n0 * Dm;

  floatx4 zero4 = {0.f, 0.f, 0.f, 0.f};
  floatx4 accf[4][4], accg[4][4];
#pragma unroll
  for (int i = 0; i < 4; i++)
#pragma unroll
    for (int j = 0; j < 4; j++) { accf[i][j] = zero4; accg[i][j] = zero4; }

  int wm = (wave & 1) * 64, wn = (wave >> 1) * 64;

  for (int k0 = 0; k0 < Dm; k0 += 64) {
#pragma unroll
    for (int i = 0; i < 4; i++) {
      int c = (wave * 4 + i) * 64 + lane;
      int row = c >> 3, col = (c & 7) * 8;
      int lo = (wave * 4 + i) * 512;  // elements; lane*16B appended by HW
      load_lds16(Ab + (size_t)row * Dm + k0 + col, a_s + lo);
      load_lds16(Bf + (size_t)row * Dm + k0 + col, bf_s + lo);
      load_lds16(Bg + (size_t)row * Dm + k0 + col, bg_s + lo);
    }
    __syncthreads();
#pragma unroll
    for (int kk = 0; kk < 64; kk += 32) {
      shortx8 af[4], bff[4], bgf[4];
#pragma unroll
      for (int mi = 0; mi < 4; mi++)
        af[mi] = *(const shortx8*)(a_s + (wm + mi * 16 + l15) * 64 + kk + quad * 8);
#pragma unroll
      for (int ni = 0; ni < 4; ni++) {
        bff[ni] = *(const shortx8*)(bf_s + (wn + ni * 16 + l15) * 64 + kk + quad * 8);
        bgf[ni] = *(const shortx8*)(bg_s + (wn + ni * 16 + l15) * 64 + kk + quad * 8);
      }
#pragma unroll
      for (int mi = 0; mi < 4; mi++)
#pragma unroll
        for (int ni = 0; ni < 4; ni++) {
          accf[mi][ni] = __builtin_amdgcn_mfma_f32_16x16x32_bf16(af[mi], bff[ni], accf[mi][ni], 0, 0, 0);
          accg[mi][ni] = __builtin_amdgcn_mfma_f32_16x16x32_bf16(af[mi], bgf[ni], accg[mi][ni], 0, 0, 0);
        }
    }
    __syncthreads();
  }
  // epilogue: silu-combine, transpose via LDS, coalesced bf16 store
  unsigned short* h_s = lds;  // 128*128 bf16 = 32KB
#pragma unroll
  for (int mi = 0; mi < 4; mi++)
#pragma unroll
    for (int ni = 0; ni < 4; ni++)
#pragma unroll
      for (int r = 0; r < 4; r++) {
        float fc = accf[mi][ni][r], gt = accg[mi][ni][r];
        float h = fc * (gt / (1.0f + __expf(-gt)));
        int m = wm + mi * 16 + quad * 4 + r;
        int n = wn + ni * 16 + l15;
        h_s[m * 128 + n] = f2bf(h);
      }
  __syncthreads();
#pragma unroll
  for (int i = 0; i < 8; i++) {
    int c = i * 256 + tid;          // 2048 chunks of 8 elems
    int row = c >> 4, col = (c & 15) * 8;
    *(shortx8*)(hg + (size_t)(rt * 128 + row) * Hd + n0 + col) =
        *(const shortx8*)(h_s + row * 128 + col);
  }
}

// ---------- GEMM2: y[t] += rw * (h @ Wproj)   (shared expert has rw=1) ----------
__global__ __launch_bounds__(256) void gemm_proj(
    const unsigned short* __restrict__ hg,   // [ROWS_CAP][Hd]
    const unsigned short* __restrict__ wpr,  // [9][Dm][Hd] (transposed: row=n, col=k)
    const int* __restrict__ tile_e,
    const int* __restrict__ rows,
    const float* __restrict__ rw,
    float* __restrict__ y)
{
  int rt = blockIdx.y;
  int e = tile_e[rt];
  if (e < 0) return;
  int n0 = blockIdx.x * 128;
  __shared__ __align__(16) unsigned short lds[2 * 128 * 64];
  unsigned short* a_s = lds;
  unsigned short* b_s = lds + 128 * 64;
  int tid = threadIdx.x;
  int wave = tid >> 6, lane = tid & 63;
  int quad = lane >> 4, l15 = lane & 15;
  const unsigned short* Ab = hg + (size_t)rt * 128 * Hd;
  const unsigned short* Bb = wpr + (size_t)e * Dm * Hd + (size_t)n0 * Hd;

  floatx4 zero4 = {0.f, 0.f, 0.f, 0.f};
  floatx4 acc[4][4];
#pragma unroll
  for (int i = 0; i < 4; i++)
#pragma unroll
    for (int j = 0; j < 4; j++) acc[i][j] = zero4;

  int wm = (wave & 1) * 64, wn = (wave >> 1) * 64;

  for (int k0 = 0; k0 < Hd; k0 += 64) {
#pragma unroll
    for (int i = 0; i < 4; i++) {
      int c = (wave * 4 + i) * 64 + lane;
      int row = c >> 3, col = (c & 7) * 8;
      int lo = (wave * 4 + i) * 512;
      load_lds16(Ab + (size_t)row * Hd + k0 + col, a_s + lo);
      load_lds16(Bb + (size_t)row * Hd + k0 + col, b_s + lo);
    }
    __syncthreads();
#pragma unroll
    for (int kk = 0; kk < 64; kk += 32) {
      shortx8 af[4], bf[4];
#pragma unroll
      for (int mi = 0; mi < 4; mi++)
        af[mi] = *(const shortx8*)(a_s + (wm + mi * 16 + l15) * 64 + kk + quad * 8);
#pragma unroll
      for (int ni = 0; ni < 4; ni++)
        bf[ni] = *(const shortx8*)(b_s + (wn + ni * 16 + l15) * 64 + kk + quad * 8);
#pragma unroll
      for (int mi = 0; mi < 4; mi++)
#pragma unroll
        for (int ni = 0; ni < 4; ni++)
          acc[mi][ni] = __builtin_amdgcn_mfma_f32_16x16x32_bf16(af[mi], bf[ni], acc[mi][ni], 0, 0, 0);
    }
    __syncthreads();
  }
  // epilogue: weighted atomic scatter into y
  int grbase = rt * 128;
#pragma unroll
  for (int mi = 0; mi < 4; mi++) {
#pragma unroll
    for (int r = 0; r < 4; r++) {
      int gr = grbase + wm + mi * 16 + quad * 4 + r;
      int t = rows[gr];
      float w = rw[gr];
      if (w != 0.0f) {
#pragma unroll
        for (int ni = 0; ni < 4; ni++) {
          int col = n0 + wn + ni * 16 + l15;
          unsafeAtomicAdd(&y[(size_t)t * Dm + col], w * acc[mi][ni][r]);
        }
      }
    }
  }
}

// ---------- finalize: lb_loss + counts into output tail ----------
__global__ void finalize(const int* __restrict__ counts, const double* __restrict__ psum,
                         float* __restrict__ out_tail) {
  int tid = threadIdx.x;
  if (tid == 0) {
    double acc = 0.0;
    for (int e = 0; e < 8; e++) {
      double f = counts[e] / (double)(Tt * 2);
      double p = psum[e] / (double)Tt;
      acc += f * p;
    }
    out_tail[0] = (float)(8.0 * acc - 1.0);
  }
  if (tid < 8) out_tail[1 + tid] = (float)counts[tid];
}

// ---------- launch ----------
extern "C" void kernel_launch(void* const* d_in, const int* in_sizes, int n_in,
                              void* d_out, int out_size, void* d_ws, size_t ws_size,
                              hipStream_t stream) {
  const float* x        = (const float*)d_in[0];
  const float* w_router = (const float*)d_in[1];
  const float* w_fc     = (const float*)d_in[2];
  const float* w_gate   = (const float*)d_in[3];
  const float* w_proj   = (const float*)d_in[4];
  const float* w_sfc    = (const float*)d_in[5];
  const float* w_sgate  = (const float*)d_in[6];
  const float* w_sproj  = (const float*)d_in[7];
  float* y = (float*)d_out;

  char* p = (char*)d_ws;
  auto alloc = [&](size_t bytes) {
    char* r = p;
    p += (bytes + 255) & ~(size_t)255;
    return r;
  };
  unsigned short* wfc_t = (unsigned short*)alloc((size_t)9 * Hd * Dm * 2);
  unsigned short* wgt_t = (unsigned short*)alloc((size_t)9 * Hd * Dm * 2);
  unsigned short* wpr_t = (unsigned short*)alloc((size_t)9 * Dm * Hd * 2);
  unsigned short* xg    = (unsigned short*)alloc((size_t)ROWS_CAP * Dm * 2);
  unsigned short* hg    = (unsigned short*)alloc((size_t)ROWS_CAP * Hd * 2);
  char* zbase = p;  // start of zero-initialized block
  int* rows    = (int*)alloc(ROWS_CAP * 4);
  float* rwv   = (float*)alloc(ROWS_CAP * 4);
  int* counts  = (int*)alloc(64);
  int* fill    = (int*)alloc(64);
  double* psum = (double*)alloc(64);
  size_t zbytes = (size_t)(p - zbase);
  int* tok_exp = (int*)alloc(Tt * 2 * 4);
  float* tok_w = (float*)alloc(Tt * 2 * 4);
  int* off     = (int*)alloc(64);
  int* tile_e  = (int*)alloc(NT_CAP * 4);

  hipMemsetAsync(d_out, 0, (size_t)out_size * 4, stream);
  hipMemsetAsync(xg, 0, (size_t)ROWS_CAP * Dm * 2, stream);
  hipMemsetAsync(zbase, 0, zbytes, stream);

  dim3 tb(32, 8);
  // expert weights -> bf16 transposed, shared expert in slot 8
  tcast<<<dim3(Hd / 32, Dm / 32, 8), tb, 0, stream>>>(w_fc, wfc_t, Dm, Hd);
  tcast<<<dim3(Hd / 32, Dm / 32, 8), tb, 0, stream>>>(w_gate, wgt_t, Dm, Hd);
  tcast<<<dim3(Dm / 32, Hd / 32, 8), tb, 0, stream>>>(w_proj, wpr_t, Hd, Dm);
  tcast<<<dim3(Hd / 32, Dm / 32, 1), tb, 0, stream>>>(w_sfc, wfc_t + (size_t)8 * Hd * Dm, Dm, Hd);
  tcast<<<dim3(Hd / 32, Dm / 32, 1), tb, 0, stream>>>(w_sgate, wgt_t + (size_t)8 * Hd * Dm, Dm, Hd);
  tcast<<<dim3(Dm / 32, Hd / 32, 1), tb, 0, stream>>>(w_sproj, wpr_t + (size_t)8 * Dm * Hd, Hd, Dm);

  router_kernel<<<Tt / 4, 256, 0, stream>>>(x, w_router, tok_exp, tok_w, counts, psum);
  make_offsets<<<1, 64, 0, stream>>>(counts, off, tile_e);
  gather_kernel<<<Tt, 256, 0, stream>>>(x, tok_exp, tok_w, off, fill, rows, rwv, xg);
  gemm_fcgate<<<dim3(Hd / 128, NT_CAP), 256, 0, stream>>>(xg, wfc_t, wgt_t, tile_e, hg);
  gemm_proj<<<dim3(Dm / 128, NT_CAP), 256, 0, stream>>>(hg, wpr_t, tile_e, rows, rwv, y);
  finalize<<<1, 64, 0, stream>>>(counts, psum, y + YN);
}

// Round 2
// 1337.068 us; speedup vs baseline: 1.0506x; 1.0506x over previous
//
#include <hip/hip_runtime.h>

typedef __attribute__((ext_vector_type(4))) float floatx4;
typedef __attribute__((ext_vector_type(8))) short shortx8;

#define AS1 __attribute__((address_space(1)))
#define AS3 __attribute__((address_space(3)))

constexpr int Tt = 4096;       // tokens (2*2048)
constexpr int Dm = 1024;       // d_model
constexpr int Hd = 4096;       // hidden
constexpr int ROWS_CAP = 13312; // 104 tiles * 128: 8192 routed + pad + 4096 shared
constexpr int NT_CAP = 104;
constexpr int YN = Tt * Dm;

// ---------- helpers ----------
__device__ __forceinline__ unsigned short f2bf(float f) {
  unsigned u = __builtin_bit_cast(unsigned, f);
  u = (u + 0x7fffu + ((u >> 16) & 1u)) >> 16;  // round-to-nearest-even
  return (unsigned short)u;
}

__device__ __forceinline__ void load_lds16(const unsigned short* g, unsigned short* l) {
  __builtin_amdgcn_global_load_lds((const AS1 unsigned int*)g, (AS3 unsigned int*)l, 16, 0, 0);
}

// ---------- cast + transpose fp32 [R][C] -> bf16 [C][R], batched over z ----------
__global__ void tcast(const float* __restrict__ in, unsigned short* __restrict__ out,
                      int R, int C) {
  __shared__ float tile[32][33];
  size_t mat = blockIdx.z;
  const float* ip = in + mat * (size_t)R * C;
  unsigned short* op = out + mat * (size_t)R * C;
  int c0 = blockIdx.x * 32, r0 = blockIdx.y * 32;
  int tx = threadIdx.x, ty = threadIdx.y;  // block (32,8)
#pragma unroll
  for (int i = ty; i < 32; i += 8)
    tile[i][tx] = ip[(size_t)(r0 + i) * C + (c0 + tx)];
  __syncthreads();
#pragma unroll
  for (int i = ty; i < 32; i += 8)
    op[(size_t)(c0 + i) * R + (r0 + tx)] = f2bf(tile[tx][i]);
}

// ---------- router: fp32 exact; 1 wave per token ----------
__global__ void router_kernel(const float* __restrict__ x, const float* __restrict__ wr,
                              int* __restrict__ tok_exp, float* __restrict__ tok_w,
                              int* __restrict__ counts, double* __restrict__ psum) {
  int wave = threadIdx.x >> 6, lane = threadIdx.x & 63;
  int t = blockIdx.x * 4 + wave;
  const float* xp = x + (size_t)t * Dm;
  float xi[16];
#pragma unroll
  for (int j = 0; j < 16; j++) xi[j] = xp[lane + j * 64];
  float sc[8];
#pragma unroll
  for (int e = 0; e < 8; e++) {
    const float* wp = wr + e * Dm;
    float acc = 0.f;
#pragma unroll
    for (int j = 0; j < 16; j++) acc += xi[j] * wp[lane + j * 64];
#pragma unroll
    for (int s = 32; s; s >>= 1) acc += __shfl_xor(acc, s, 64);
    sc[e] = acc;
  }
  // softmax (all lanes redundantly)
  float m = sc[0];
#pragma unroll
  for (int e = 1; e < 8; e++) m = fmaxf(m, sc[e]);
  float sum = 0.f;
#pragma unroll
  for (int e = 0; e < 8; e++) { sc[e] = __expf(sc[e] - m); sum += sc[e]; }
  float inv = 1.0f / sum;
#pragma unroll
  for (int e = 0; e < 8; e++) sc[e] *= inv;
  // group scores: G=4 groups of 2; keep top-2 groups (lowest index wins ties)
  float gs[4];
#pragma unroll
  for (int g = 0; g < 4; g++) gs[g] = fmaxf(sc[2 * g], sc[2 * g + 1]);
  int g1 = -1, g2 = -1; float b1 = -1e30f, b2 = -1e30f;
#pragma unroll
  for (int g = 0; g < 4; g++) if (gs[g] > b1) { b1 = gs[g]; g1 = g; }
#pragma unroll
  for (int g = 0; g < 4; g++) if (g != g1 && gs[g] > b2) { b2 = gs[g]; g2 = g; }
  // top-2 experts among kept groups
  int e1 = -1, e2 = -1; float c1 = -1e30f, c2 = -1e30f;
#pragma unroll
  for (int e = 0; e < 8; e++) {
    int g = e >> 1; bool keep = (g == g1) || (g == g2);
    if (keep && sc[e] > c1) { c1 = sc[e]; e1 = e; }
  }
#pragma unroll
  for (int e = 0; e < 8; e++) {
    int g = e >> 1; bool keep = (g == g1) || (g == g2);
    if (keep && e != e1 && sc[e] > c2) { c2 = sc[e]; e2 = e; }
  }
  if (lane == 0) {
    tok_exp[t * 2] = e1; tok_w[t * 2] = c1;
    tok_exp[t * 2 + 1] = e2; tok_w[t * 2 + 1] = c2;
    atomicAdd(&counts[e1], 1);
    atomicAdd(&counts[e2], 1);
  }
  float mysc = 0.f;
#pragma unroll
  for (int e = 0; e < 8; e++) if (e == lane) mysc = sc[e];
  if (lane < 8) atomicAdd(&psum[lane], (double)mysc);
}

// ---------- offsets + tile->expert map (serial, tiny) ----------
__global__ void make_offsets(const int* __restrict__ counts, int* __restrict__ off,
                             int* __restrict__ tile_e) {
  if (threadIdx.x == 0) {
    int o[10];
    o[0] = 0;
    for (int e = 0; e < 8; e++) o[e + 1] = o[e] + ((counts[e] + 127) & ~127);
    o[9] = o[8] + Tt;  // shared-expert segment (expert id 8), exactly Tt rows
    for (int e = 0; e < 10; e++) off[e] = o[e];
    int nt = o[9] >> 7;
    for (int i = 0; i < NT_CAP; i++) {
      int te = -1;
      if (i < nt) {
        int r = i << 7;
        for (int e = 0; e < 9; e++)
          if (r >= o[e] && r < o[e + 1]) te = e;
      }
      tile_e[i] = te;
    }
  }
}

// ---------- gather token rows (bf16) into padded per-expert segments ----------
__global__ void gather_kernel(const float* __restrict__ x, const int* __restrict__ tok_exp,
                              const float* __restrict__ tok_w, const int* __restrict__ off,
                              int* __restrict__ fill, int* __restrict__ rows,
                              float* __restrict__ rw, unsigned short* __restrict__ xg) {
  int t = blockIdx.x;
  int tid = threadIdx.x;
  __shared__ int spos[3];
  if (tid < 2) {
    int e = tok_exp[t * 2 + tid];
    int p = off[e] + atomicAdd(&fill[e], 1);
    spos[tid] = p; rows[p] = t; rw[p] = tok_w[t * 2 + tid];
  } else if (tid == 2) {
    int p = off[8] + t;
    spos[2] = p; rows[p] = t; rw[p] = 1.0f;
  }
  __syncthreads();
  float4 v = ((const float4*)(x + (size_t)t * Dm))[tid];  // 256 threads * float4 = 1024
  ushort4 b;
  b.x = f2bf(v.x); b.y = f2bf(v.y); b.z = f2bf(v.z); b.w = f2bf(v.w);
#pragma unroll
  for (int k = 0; k < 3; k++)
    ((ushort4*)(xg + (size_t)spos[k] * Dm))[tid] = b;
}

// ---------- GEMM1: h = (Xg @ Wfc) * silu(Xg @ Wgate), bf16 out ----------
// 128x128 tile, BK=64, 4 waves (2x2 of 64x64), mfma 16x16x32 bf16.
// LDS layout XOR-swizzled: chunk (row, cl) stored at physical chunk cl^(row&7)
// so ds_read_b128 lands 8 lanes per 4-bank group (the floor) instead of 16.
__global__ __launch_bounds__(256) void gemm_fcgate(
    const unsigned short* __restrict__ xg,   // [ROWS_CAP][Dm]
    const unsigned short* __restrict__ wfc,  // [9][Hd][Dm]  (transposed: row=n, col=k)
    const unsigned short* __restrict__ wgt,  // [9][Hd][Dm]
    const int* __restrict__ tile_e,
    unsigned short* __restrict__ hg)         // [ROWS_CAP][Hd]
{
  int rt = blockIdx.y;
  int e = tile_e[rt];
  if (e < 0) return;
  int n0 = blockIdx.x * 128;
  __shared__ __align__(16) unsigned short lds[3 * 128 * 64];
  unsigned short* a_s = lds;
  unsigned short* bf_s = lds + 128 * 64;
  unsigned short* bg_s = lds + 2 * 128 * 64;
  int tid = threadIdx.x;
  int wave = tid >> 6, lane = tid & 63;
  int quad = lane >> 4, l15 = lane & 15;
  int sx = l15 & 7;  // fragment-read XOR key (row & 7)
  const unsigned short* Ab = xg + (size_t)rt * 128 * Dm;
  const unsigned short* Bf = wfc + (size_t)e * Hd * Dm + (size_t)n0 * Dm;
  const unsigned short* Bg = wgt + (size_t)e * Hd * Dm + (size_t)n0 * Dm;

  floatx4 zero4 = {0.f, 0.f, 0.f, 0.f};
  floatx4 accf[4][4], accg[4][4];
#pragma unroll
  for (int i = 0; i < 4; i++)
#pragma unroll
    for (int j = 0; j < 4; j++) { accf[i][j] = zero4; accg[i][j] = zero4; }

  int wm = (wave & 1) * 64, wn = (wave >> 1) * 64;

  for (int k0 = 0; k0 < Dm; k0 += 64) {
#pragma unroll
    for (int i = 0; i < 4; i++) {
      int c = (wave * 4 + i) * 64 + lane;
      int row = c >> 3;
      int col = (((c & 7) ^ (row & 7)) << 3);  // swizzled source column
      int lo = (wave * 4 + i) * 512;  // elements; lane*16B appended by HW
      load_lds16(Ab + (size_t)row * Dm + k0 + col, a_s + lo);
      load_lds16(Bf + (size_t)row * Dm + k0 + col, bf_s + lo);
      load_lds16(Bg + (size_t)row * Dm + k0 + col, bg_s + lo);
    }
    __syncthreads();
#pragma unroll
    for (int kk = 0; kk < 64; kk += 32) {
      shortx8 af[4], bff[4], bgf[4];
      int cl = (kk >> 3) + quad;
      int co = ((cl ^ sx) << 3);
#pragma unroll
      for (int mi = 0; mi < 4; mi++)
        af[mi] = *(const shortx8*)(a_s + (wm + mi * 16 + l15) * 64 + co);
#pragma unroll
      for (int ni = 0; ni < 4; ni++) {
        bff[ni] = *(const shortx8*)(bf_s + (wn + ni * 16 + l15) * 64 + co);
        bgf[ni] = *(const shortx8*)(bg_s + (wn + ni * 16 + l15) * 64 + co);
      }
#pragma unroll
      for (int mi = 0; mi < 4; mi++)
#pragma unroll
        for (int ni = 0; ni < 4; ni++) {
          accf[mi][ni] = __builtin_amdgcn_mfma_f32_16x16x32_bf16(af[mi], bff[ni], accf[mi][ni], 0, 0, 0);
          accg[mi][ni] = __builtin_amdgcn_mfma_f32_16x16x32_bf16(af[mi], bgf[ni], accg[mi][ni], 0, 0, 0);
        }
    }
    __syncthreads();
  }
  // epilogue: silu-combine, transpose via LDS (stride 136 = 16B-aligned, bank-spread)
  unsigned short* h_s = lds;
#pragma unroll
  for (int mi = 0; mi < 4; mi++)
#pragma unroll
    for (int ni = 0; ni < 4; ni++)
#pragma unroll
      for (int r = 0; r < 4; r++) {
        float fc = accf[mi][ni][r], gt = accg[mi][ni][r];
        float h = fc * (gt / (1.0f + __expf(-gt)));
        int m = wm + mi * 16 + quad * 4 + r;
        int n = wn + ni * 16 + l15;
        h_s[m * 136 + n] = f2bf(h);
      }
  __syncthreads();
#pragma unroll
  for (int i = 0; i < 8; i++) {
    int c = i * 256 + tid;          // 2048 chunks of 8 elems
    int row = c >> 4, col = (c & 15) * 8;
    *(shortx8*)(hg + (size_t)(rt * 128 + row) * Hd + n0 + col) =
        *(const shortx8*)(h_s + row * 136 + col);
  }
}

// ---------- GEMM2: y[t] += rw * (h @ Wproj)   (shared expert has rw=1) ----------
__global__ __launch_bounds__(256) void gemm_proj(
    const unsigned short* __restrict__ hg,   // [ROWS_CAP][Hd]
    const unsigned short* __restrict__ wpr,  // [9][Dm][Hd] (transposed: row=n, col=k)
    const int* __restrict__ tile_e,
    const int* __restrict__ rows,
    const float* __restrict__ rw,
    float* __restrict__ y)
{
  int rt = blockIdx.y;
  int e = tile_e[rt];
  if (e < 0) return;
  int n0 = blockIdx.x * 128;
  __shared__ __align__(16) unsigned short lds[2 * 128 * 64];
  unsigned short* a_s = lds;
  unsigned short* b_s = lds + 128 * 64;
  int tid = threadIdx.x;
  int wave = tid >> 6, lane = tid & 63;
  int quad = lane >> 4, l15 = lane & 15;
  int sx = l15 & 7;
  const unsigned short* Ab = hg + (size_t)rt * 128 * Hd;
  const unsigned short* Bb = wpr + (size_t)e * Dm * Hd + (size_t)n0 * Hd;

  floatx4 zero4 = {0.f, 0.f, 0.f, 0.f};
  floatx4 acc[4][4];
#pragma unroll
  for (int i = 0; i < 4; i++)
#pragma unroll
    for (int j = 0; j < 4; j++) acc[i][j] = zero4;

  int wm = (wave & 1) * 64, wn = (wave >> 1) * 64;

  for (int k0 = 0; k0 < Hd; k0 += 64) {
#pragma unroll
    for (int i = 0; i < 4; i++) {
      int c = (wave * 4 + i) * 64 + lane;
      int row = c >> 3;
      int col = (((c & 7) ^ (row & 7)) << 3);
      int lo = (wave * 4 + i) * 512;
      load_lds16(Ab + (size_t)row * Hd + k0 + col, a_s + lo);
      load_lds16(Bb + (size_t)row * Hd + k0 + col, b_s + lo);
    }
    __syncthreads();
#pragma unroll
    for (int kk = 0; kk < 64; kk += 32) {
      shortx8 af[4], bf[4];
      int cl = (kk >> 3) + quad;
      int co = ((cl ^ sx) << 3);
#pragma unroll
      for (int mi = 0; mi < 4; mi++)
        af[mi] = *(const shortx8*)(a_s + (wm + mi * 16 + l15) * 64 + co);
#pragma unroll
      for (int ni = 0; ni < 4; ni++)
        bf[ni] = *(const shortx8*)(b_s + (wn + ni * 16 + l15) * 64 + co);
#pragma unroll
      for (int mi = 0; mi < 4; mi++)
#pragma unroll
        for (int ni = 0; ni < 4; ni++)
          acc[mi][ni] = __builtin_amdgcn_mfma_f32_16x16x32_bf16(af[mi], bf[ni], acc[mi][ni], 0, 0, 0);
    }
    __syncthreads();
  }
  // epilogue: weighted atomic scatter into y
  int grbase = rt * 128;
#pragma unroll
  for (int mi = 0; mi < 4; mi++) {
#pragma unroll
    for (int r = 0; r < 4; r++) {
      int gr = grbase + wm + mi * 16 + quad * 4 + r;
      int t = rows[gr];
      float w = rw[gr];
      if (w != 0.0f) {
#pragma unroll
        for (int ni = 0; ni < 4; ni++) {
          int col = n0 + wn + ni * 16 + l15;
          unsafeAtomicAdd(&y[(size_t)t * Dm + col], w * acc[mi][ni][r]);
        }
      }
    }
  }
}

// ---------- finalize: lb_loss + counts into output tail ----------
__global__ void finalize(const int* __restrict__ counts, const double* __restrict__ psum,
                         float* __restrict__ out_tail) {
  int tid = threadIdx.x;
  if (tid == 0) {
    double acc = 0.0;
    for (int e = 0; e < 8; e++) {
      double f = counts[e] / (double)(Tt * 2);
      double p = psum[e] / (double)Tt;
      acc += f * p;
    }
    out_tail[0] = (float)(8.0 * acc - 1.0);
  }
  if (tid < 8) out_tail[1 + tid] = (float)counts[tid];
}

// ---------- launch ----------
extern "C" void kernel_launch(void* const* d_in, const int* in_sizes, int n_in,
                              void* d_out, int out_size, void* d_ws, size_t ws_size,
                              hipStream_t stream) {
  const float* x        = (const float*)d_in[0];
  const float* w_router = (const float*)d_in[1];
  const float* w_fc     = (const float*)d_in[2];
  const float* w_gate   = (const float*)d_in[3];
  const float* w_proj   = (const float*)d_in[4];
  const float* w_sfc    = (const float*)d_in[5];
  const float* w_sgate  = (const float*)d_in[6];
  const float* w_sproj  = (const float*)d_in[7];
  float* y = (float*)d_out;

  char* p = (char*)d_ws;
  auto alloc = [&](size_t bytes) {
    char* r = p;
    p += (bytes + 255) & ~(size_t)255;
    return r;
  };
  unsigned short* wfc_t = (unsigned short*)alloc((size_t)9 * Hd * Dm * 2);
  unsigned short* wgt_t = (unsigned short*)alloc((size_t)9 * Hd * Dm * 2);
  unsigned short* wpr_t = (unsigned short*)alloc((size_t)9 * Dm * Hd * 2);
  unsigned short* xg    = (unsigned short*)alloc((size_t)ROWS_CAP * Dm * 2);
  unsigned short* hg    = (unsigned short*)alloc((size_t)ROWS_CAP * Hd * 2);
  char* zbase = p;  // start of zero-initialized block
  int* rows    = (int*)alloc(ROWS_CAP * 4);
  float* rwv   = (float*)alloc(ROWS_CAP * 4);
  int* counts  = (int*)alloc(64);
  int* fill    = (int*)alloc(64);
  double* psum = (double*)alloc(64);
  size_t zbytes = (size_t)(p - zbase);
  int* tok_exp = (int*)alloc(Tt * 2 * 4);
  float* tok_w = (float*)alloc(Tt * 2 * 4);
  int* off     = (int*)alloc(64);
  int* tile_e  = (int*)alloc(NT_CAP * 4);

  hipMemsetAsync(d_out, 0, (size_t)out_size * 4, stream);
  hipMemsetAsync(xg, 0, (size_t)ROWS_CAP * Dm * 2, stream);
  hipMemsetAsync(zbase, 0, zbytes, stream);

  dim3 tb(32, 8);
  // expert weights -> bf16 transposed, shared expert in slot 8
  tcast<<<dim3(Hd / 32, Dm / 32, 8), tb, 0, stream>>>(w_fc, wfc_t, Dm, Hd);
  tcast<<<dim3(Hd / 32, Dm / 32, 8), tb, 0, stream>>>(w_gate, wgt_t, Dm, Hd);
  tcast<<<dim3(Dm / 32, Hd / 32, 8), tb, 0, stream>>>(w_proj, wpr_t, Hd, Dm);
  tcast<<<dim3(Hd / 32, Dm / 32, 1), tb, 0, stream>>>(w_sfc, wfc_t + (size_t)8 * Hd * Dm, Dm, Hd);
  tcast<<<dim3(Hd / 32, Dm / 32, 1), tb, 0, stream>>>(w_sgate, wgt_t + (size_t)8 * Hd * Dm, Dm, Hd);
  tcast<<<dim3(Dm / 32, Hd / 32, 1), tb, 0, stream>>>(w_sproj, wpr_t + (size_t)8 * Dm * Hd, Hd, Dm);

  router_kernel<<<Tt / 4, 256, 0, stream>>>(x, w_router, tok_exp, tok_w, counts, psum);
  make_offsets<<<1, 64, 0, stream>>>(counts, off, tile_e);
  gather_kernel<<<Tt, 256, 0, stream>>>(x, tok_exp, tok_w, off, fill, rows, rwv, xg);
  gemm_fcgate<<<dim3(Hd / 128, NT_CAP), 256, 0, stream>>>(xg, wfc_t, wgt_t, tile_e, hg);
  gemm_proj<<<dim3(Dm / 128, NT_CAP), 256, 0, stream>>>(hg, wpr_t, tile_e, rows, rwv, y);
  finalize<<<1, 64, 0, stream>>>(counts, psum, y + YN);
}

// Round 3
// 1106.631 us; speedup vs baseline: 1.2693x; 1.2082x over previous
//
#include <hip/hip_runtime.h>

typedef __attribute__((ext_vector_type(4))) float floatx4;
typedef __attribute__((ext_vector_type(8))) short shortx8;

#define AS1 __attribute__((address_space(1)))
#define AS3 __attribute__((address_space(3)))

constexpr int Tt = 4096;       // tokens (2*2048)
constexpr int Dm = 1024;       // d_model
constexpr int Hd = 4096;       // hidden
constexpr int ROWS_CAP = 13312; // 104 tiles * 128: 8192 routed + pad + 4096 shared
constexpr int NT_CAP = 104;
constexpr int YN = Tt * Dm;

// ---------- helpers ----------
__device__ __forceinline__ unsigned short f2bf(float f) {
  unsigned u = __builtin_bit_cast(unsigned, f);
  u = (u + 0x7fffu + ((u >> 16) & 1u)) >> 16;  // round-to-nearest-even
  return (unsigned short)u;
}

__device__ __forceinline__ void load_lds16(const unsigned short* g, unsigned short* l) {
  __builtin_amdgcn_global_load_lds((const AS1 unsigned int*)g, (AS3 unsigned int*)l, 16, 0, 0);
}

// ---------- cast + transpose fp32 [R][C] -> bf16 [C][R], batched over z ----------
__global__ void tcast(const float* __restrict__ in, unsigned short* __restrict__ out,
                      int R, int C) {
  __shared__ float tile[32][33];
  size_t mat = blockIdx.z;
  const float* ip = in + mat * (size_t)R * C;
  unsigned short* op = out + mat * (size_t)R * C;
  int c0 = blockIdx.x * 32, r0 = blockIdx.y * 32;
  int tx = threadIdx.x, ty = threadIdx.y;  // block (32,8)
#pragma unroll
  for (int i = ty; i < 32; i += 8)
    tile[i][tx] = ip[(size_t)(r0 + i) * C + (c0 + tx)];
  __syncthreads();
#pragma unroll
  for (int i = ty; i < 32; i += 8)
    op[(size_t)(c0 + i) * R + (r0 + tx)] = f2bf(tile[tx][i]);
}

// ---------- router: fp32 exact; 1 wave per token; ticket = atomicAdd return ----------
__global__ void router_kernel(const float* __restrict__ x, const float* __restrict__ wr,
                              int* __restrict__ tok_exp, float* __restrict__ tok_w,
                              int* __restrict__ tok_tick,
                              int* __restrict__ counts, double* __restrict__ psum) {
  int wave = threadIdx.x >> 6, lane = threadIdx.x & 63;
  int t = blockIdx.x * 4 + wave;
  const float* xp = x + (size_t)t * Dm;
  float xi[16];
#pragma unroll
  for (int j = 0; j < 16; j++) xi[j] = xp[lane + j * 64];
  float sc[8];
#pragma unroll
  for (int e = 0; e < 8; e++) {
    const float* wp = wr + e * Dm;
    float acc = 0.f;
#pragma unroll
    for (int j = 0; j < 16; j++) acc += xi[j] * wp[lane + j * 64];
#pragma unroll
    for (int s = 32; s; s >>= 1) acc += __shfl_xor(acc, s, 64);
    sc[e] = acc;
  }
  // softmax (all lanes redundantly)
  float m = sc[0];
#pragma unroll
  for (int e = 1; e < 8; e++) m = fmaxf(m, sc[e]);
  float sum = 0.f;
#pragma unroll
  for (int e = 0; e < 8; e++) { sc[e] = __expf(sc[e] - m); sum += sc[e]; }
  float inv = 1.0f / sum;
#pragma unroll
  for (int e = 0; e < 8; e++) sc[e] *= inv;
  // group scores: G=4 groups of 2; keep top-2 groups (lowest index wins ties)
  float gs[4];
#pragma unroll
  for (int g = 0; g < 4; g++) gs[g] = fmaxf(sc[2 * g], sc[2 * g + 1]);
  int g1 = -1, g2 = -1; float b1 = -1e30f, b2 = -1e30f;
#pragma unroll
  for (int g = 0; g < 4; g++) if (gs[g] > b1) { b1 = gs[g]; g1 = g; }
#pragma unroll
  for (int g = 0; g < 4; g++) if (g != g1 && gs[g] > b2) { b2 = gs[g]; g2 = g; }
  // top-2 experts among kept groups
  int e1 = -1, e2 = -1; float c1 = -1e30f, c2 = -1e30f;
#pragma unroll
  for (int e = 0; e < 8; e++) {
    int g = e >> 1; bool keep = (g == g1) || (g == g2);
    if (keep && sc[e] > c1) { c1 = sc[e]; e1 = e; }
  }
#pragma unroll
  for (int e = 0; e < 8; e++) {
    int g = e >> 1; bool keep = (g == g1) || (g == g2);
    if (keep && e != e1 && sc[e] > c2) { c2 = sc[e]; e2 = e; }
  }
  if (lane == 0) {
    int k1 = atomicAdd(&counts[e1], 1);
    int k2 = atomicAdd(&counts[e2], 1);
    tok_exp[t * 2] = e1; tok_w[t * 2] = c1; tok_tick[t * 2] = k1;
    tok_exp[t * 2 + 1] = e2; tok_w[t * 2 + 1] = c2; tok_tick[t * 2 + 1] = k2;
  }
  // psum: block-reduce in LDS, one f64 atomic per expert per block
  __shared__ float ps[4][8];
  float mysc = 0.f;
#pragma unroll
  for (int e = 0; e < 8; e++) if (e == lane) mysc = sc[e];
  if (lane < 8) ps[wave][lane] = mysc;
  __syncthreads();
  if (wave == 0 && lane < 8) {
    float s = ps[0][lane] + ps[1][lane] + ps[2][lane] + ps[3][lane];
    atomicAdd(&psum[lane], (double)s);
  }
}

// ---------- offsets + tile->expert map (serial, tiny) ----------
__global__ void make_offsets(const int* __restrict__ counts, int* __restrict__ off,
                             int* __restrict__ tile_e) {
  if (threadIdx.x == 0) {
    int o[10];
    o[0] = 0;
    for (int e = 0; e < 8; e++) o[e + 1] = o[e] + ((counts[e] + 127) & ~127);
    o[9] = o[8] + Tt;  // shared-expert segment (expert id 8), exactly Tt rows
    for (int e = 0; e < 10; e++) off[e] = o[e];
    int nt = o[9] >> 7;
    for (int i = 0; i < NT_CAP; i++) {
      int te = -1;
      if (i < nt) {
        int r = i << 7;
        for (int e = 0; e < 9; e++)
          if (r >= o[e] && r < o[e + 1]) te = e;
      }
      tile_e[i] = te;
    }
  }
}

// ---------- gather token rows (bf16) into padded per-expert segments ----------
__global__ void gather_kernel(const float* __restrict__ x, const int* __restrict__ tok_exp,
                              const float* __restrict__ tok_w, const int* __restrict__ tok_tick,
                              const int* __restrict__ off,
                              int* __restrict__ rows, float* __restrict__ rw,
                              unsigned short* __restrict__ xg) {
  int t = blockIdx.x;
  int tid = threadIdx.x;
  __shared__ int spos[3];
  if (tid < 2) {
    int e = tok_exp[t * 2 + tid];
    int p = off[e] + tok_tick[t * 2 + tid];
    spos[tid] = p; rows[p] = t; rw[p] = tok_w[t * 2 + tid];
  } else if (tid == 2) {
    int p = off[8] + t;
    spos[2] = p; rows[p] = t; rw[p] = 1.0f;
  }
  __syncthreads();
  float4 v = ((const float4*)(x + (size_t)t * Dm))[tid];  // 256 threads * float4 = 1024
  ushort4 b;
  b.x = f2bf(v.x); b.y = f2bf(v.y); b.z = f2bf(v.z); b.w = f2bf(v.w);
#pragma unroll
  for (int k = 0; k < 3; k++)
    ((ushort4*)(xg + (size_t)spos[k] * Dm))[tid] = b;
}

// ---------- GEMM1: h = (Xg @ Wfc) * silu(Xg @ Wgate), bf16 out ----------
// 128x64 tile (N-split for occupancy: dual acc = 64 AGPRs/wave), BK=64,
// 4 waves (2x2, wave tile 64x32 per matrix), mfma 16x16x32 bf16.
// LDS XOR-swizzled (chunk cl stored at cl^(row&7)) -> near-zero bank conflicts.
__global__ __launch_bounds__(256) void gemm_fcgate(
    const unsigned short* __restrict__ xg,   // [ROWS_CAP][Dm]
    const unsigned short* __restrict__ wfc,  // [9][Hd][Dm]  (row=n, col=k)
    const unsigned short* __restrict__ wgt,  // [9][Hd][Dm]
    const int* __restrict__ tile_e,
    unsigned short* __restrict__ hg)         // [ROWS_CAP][Hd]
{
  int rt = blockIdx.y;
  int e = tile_e[rt];
  if (e < 0) return;
  int n0 = blockIdx.x * 64;
  __shared__ __align__(16) unsigned short lds[128 * 64 + 2 * 64 * 64];  // 32KB
  unsigned short* a_s = lds;
  unsigned short* bf_s = lds + 128 * 64;
  unsigned short* bg_s = lds + 128 * 64 + 64 * 64;
  int tid = threadIdx.x;
  int wave = tid >> 6, lane = tid & 63;
  int quad = lane >> 4, l15 = lane & 15;
  int sx = l15 & 7;  // fragment-read XOR key (row & 7)
  const unsigned short* Ab = xg + (size_t)rt * 128 * Dm;
  const unsigned short* Bf = wfc + (size_t)e * Hd * Dm + (size_t)n0 * Dm;
  const unsigned short* Bg = wgt + (size_t)e * Hd * Dm + (size_t)n0 * Dm;

  floatx4 zero4 = {0.f, 0.f, 0.f, 0.f};
  floatx4 accf[4][2], accg[4][2];
#pragma unroll
  for (int i = 0; i < 4; i++)
#pragma unroll
    for (int j = 0; j < 2; j++) { accf[i][j] = zero4; accg[i][j] = zero4; }

  int wm = (wave & 1) * 64, wn = (wave >> 1) * 32;

  for (int k0 = 0; k0 < Dm; k0 += 64) {
#pragma unroll
    for (int i = 0; i < 4; i++) {  // A: 128x64 = 16 wave-chunks, 4 per wave
      int c = (wave * 4 + i) * 64 + lane;
      int row = c >> 3;
      int col = (((c & 7) ^ (row & 7)) << 3);
      load_lds16(Ab + (size_t)row * Dm + k0 + col, a_s + (wave * 4 + i) * 512);
    }
#pragma unroll
    for (int i = 0; i < 2; i++) {  // Bf/Bg: 64x64 = 8 wave-chunks, 2 per wave
      int c = (wave * 2 + i) * 64 + lane;
      int row = c >> 3;
      int col = (((c & 7) ^ (row & 7)) << 3);
      load_lds16(Bf + (size_t)row * Dm + k0 + col, bf_s + (wave * 2 + i) * 512);
      load_lds16(Bg + (size_t)row * Dm + k0 + col, bg_s + (wave * 2 + i) * 512);
    }
    __syncthreads();
#pragma unroll
    for (int kk = 0; kk < 64; kk += 32) {
      shortx8 af[4], bff[2], bgf[2];
      int cl = (kk >> 3) + quad;
      int co = ((cl ^ sx) << 3);
#pragma unroll
      for (int mi = 0; mi < 4; mi++)
        af[mi] = *(const shortx8*)(a_s + (wm + mi * 16 + l15) * 64 + co);
#pragma unroll
      for (int ni = 0; ni < 2; ni++) {
        bff[ni] = *(const shortx8*)(bf_s + (wn + ni * 16 + l15) * 64 + co);
        bgf[ni] = *(const shortx8*)(bg_s + (wn + ni * 16 + l15) * 64 + co);
      }
#pragma unroll
      for (int mi = 0; mi < 4; mi++)
#pragma unroll
        for (int ni = 0; ni < 2; ni++) {
          accf[mi][ni] = __builtin_amdgcn_mfma_f32_16x16x32_bf16(af[mi], bff[ni], accf[mi][ni], 0, 0, 0);
          accg[mi][ni] = __builtin_amdgcn_mfma_f32_16x16x32_bf16(af[mi], bgf[ni], accg[mi][ni], 0, 0, 0);
        }
    }
    __syncthreads();
  }
  // epilogue: silu-combine, transpose via LDS (stride 72: 16B-aligned)
  unsigned short* h_s = lds;  // 128*72*2B = 18KB
#pragma unroll
  for (int mi = 0; mi < 4; mi++)
#pragma unroll
    for (int ni = 0; ni < 2; ni++)
#pragma unroll
      for (int r = 0; r < 4; r++) {
        float fc = accf[mi][ni][r], gt = accg[mi][ni][r];
        float h = fc * (gt / (1.0f + __expf(-gt)));
        int m = wm + mi * 16 + quad * 4 + r;
        int n = wn + ni * 16 + l15;
        h_s[m * 72 + n] = f2bf(h);
      }
  __syncthreads();
#pragma unroll
  for (int i = 0; i < 4; i++) {
    int c = i * 256 + tid;          // 1024 chunks of 8 elems
    int row = c >> 3, col = (c & 7) * 8;
    *(shortx8*)(hg + (size_t)(rt * 128 + row) * Hd + n0 + col) =
        *(const shortx8*)(h_s + row * 72 + col);
  }
}

// ---------- GEMM2: y[t] += rw * (h @ Wproj)   (shared expert has rw=1) ----------
// 128x64 tile, wave tile 64x32: acc = 32 AGPRs -> high occupancy.
__global__ __launch_bounds__(256) void gemm_proj(
    const unsigned short* __restrict__ hg,   // [ROWS_CAP][Hd]
    const unsigned short* __restrict__ wpr,  // [9][Dm][Hd] (row=n, col=k)
    const int* __restrict__ tile_e,
    const int* __restrict__ rows,
    const float* __restrict__ rw,
    float* __restrict__ y)
{
  int rt = blockIdx.y;
  int e = tile_e[rt];
  if (e < 0) return;
  int n0 = blockIdx.x * 64;
  __shared__ __align__(16) unsigned short lds[128 * 64 + 64 * 64];  // 24KB
  unsigned short* a_s = lds;
  unsigned short* b_s = lds + 128 * 64;
  int tid = threadIdx.x;
  int wave = tid >> 6, lane = tid & 63;
  int quad = lane >> 4, l15 = lane & 15;
  int sx = l15 & 7;
  const unsigned short* Ab = hg + (size_t)rt * 128 * Hd;
  const unsigned short* Bb = wpr + (size_t)e * Dm * Hd + (size_t)n0 * Hd;

  floatx4 zero4 = {0.f, 0.f, 0.f, 0.f};
  floatx4 acc[4][2];
#pragma unroll
  for (int i = 0; i < 4; i++)
#pragma unroll
    for (int j = 0; j < 2; j++) acc[i][j] = zero4;

  int wm = (wave & 1) * 64, wn = (wave >> 1) * 32;

  for (int k0 = 0; k0 < Hd; k0 += 64) {
#pragma unroll
    for (int i = 0; i < 4; i++) {
      int c = (wave * 4 + i) * 64 + lane;
      int row = c >> 3;
      int col = (((c & 7) ^ (row & 7)) << 3);
      load_lds16(Ab + (size_t)row * Hd + k0 + col, a_s + (wave * 4 + i) * 512);
    }
#pragma unroll
    for (int i = 0; i < 2; i++) {
      int c = (wave * 2 + i) * 64 + lane;
      int row = c >> 3;
      int col = (((c & 7) ^ (row & 7)) << 3);
      load_lds16(Bb + (size_t)row * Hd + k0 + col, b_s + (wave * 2 + i) * 512);
    }
    __syncthreads();
#pragma unroll
    for (int kk = 0; kk < 64; kk += 32) {
      shortx8 af[4], bf[2];
      int cl = (kk >> 3) + quad;
      int co = ((cl ^ sx) << 3);
#pragma unroll
      for (int mi = 0; mi < 4; mi++)
        af[mi] = *(const shortx8*)(a_s + (wm + mi * 16 + l15) * 64 + co);
#pragma unroll
      for (int ni = 0; ni < 2; ni++)
        bf[ni] = *(const shortx8*)(b_s + (wn + ni * 16 + l15) * 64 + co);
#pragma unroll
      for (int mi = 0; mi < 4; mi++)
#pragma unroll
        for (int ni = 0; ni < 2; ni++)
          acc[mi][ni] = __builtin_amdgcn_mfma_f32_16x16x32_bf16(af[mi], bf[ni], acc[mi][ni], 0, 0, 0);
    }
    __syncthreads();
  }
  // epilogue: weighted atomic scatter into y
  int grbase = rt * 128;
#pragma unroll
  for (int mi = 0; mi < 4; mi++) {
#pragma unroll
    for (int r = 0; r < 4; r++) {
      int gr = grbase + wm + mi * 16 + quad * 4 + r;
      int t = rows[gr];
      float w = rw[gr];
      if (w != 0.0f) {
#pragma unroll
        for (int ni = 0; ni < 2; ni++) {
          int col = n0 + wn + ni * 16 + l15;
          unsafeAtomicAdd(&y[(size_t)t * Dm + col], w * acc[mi][ni][r]);
        }
      }
    }
  }
}

// ---------- finalize: lb_loss + counts into output tail ----------
__global__ void finalize(const int* __restrict__ counts, const double* __restrict__ psum,
                         float* __restrict__ out_tail) {
  int tid = threadIdx.x;
  if (tid == 0) {
    double acc = 0.0;
    for (int e = 0; e < 8; e++) {
      double f = counts[e] / (double)(Tt * 2);
      double p = psum[e] / (double)Tt;
      acc += f * p;
    }
    out_tail[0] = (float)(8.0 * acc - 1.0);
  }
  if (tid < 8) out_tail[1 + tid] = (float)counts[tid];
}

// ---------- launch ----------
extern "C" void kernel_launch(void* const* d_in, const int* in_sizes, int n_in,
                              void* d_out, int out_size, void* d_ws, size_t ws_size,
                              hipStream_t stream) {
  const float* x        = (const float*)d_in[0];
  const float* w_router = (const float*)d_in[1];
  const float* w_fc     = (const float*)d_in[2];
  const float* w_gate   = (const float*)d_in[3];
  const float* w_proj   = (const float*)d_in[4];
  const float* w_sfc    = (const float*)d_in[5];
  const float* w_sgate  = (const float*)d_in[6];
  const float* w_sproj  = (const float*)d_in[7];
  float* y = (float*)d_out;

  char* p = (char*)d_ws;
  auto alloc = [&](size_t bytes) {
    char* r = p;
    p += (bytes + 255) & ~(size_t)255;
    return r;
  };
  unsigned short* wfc_t = (unsigned short*)alloc((size_t)9 * Hd * Dm * 2);
  unsigned short* wgt_t = (unsigned short*)alloc((size_t)9 * Hd * Dm * 2);
  unsigned short* wpr_t = (unsigned short*)alloc((size_t)9 * Dm * Hd * 2);
  unsigned short* xg    = (unsigned short*)alloc((size_t)ROWS_CAP * Dm * 2);
  unsigned short* hg    = (unsigned short*)alloc((size_t)ROWS_CAP * Hd * 2);
  char* zbase = p;  // start of zero-initialized block
  int* rows    = (int*)alloc(ROWS_CAP * 4);
  float* rwv   = (float*)alloc(ROWS_CAP * 4);
  int* counts  = (int*)alloc(64);
  double* psum = (double*)alloc(64);
  size_t zbytes = (size_t)(p - zbase);
  int* tok_exp = (int*)alloc(Tt * 2 * 4);
  float* tok_w = (float*)alloc(Tt * 2 * 4);
  int* tok_tick= (int*)alloc(Tt * 2 * 4);
  int* off     = (int*)alloc(64);
  int* tile_e  = (int*)alloc(NT_CAP * 4);

  hipMemsetAsync(d_out, 0, (size_t)out_size * 4, stream);
  hipMemsetAsync(xg, 0, (size_t)ROWS_CAP * Dm * 2, stream);
  hipMemsetAsync(zbase, 0, zbytes, stream);

  dim3 tb(32, 8);
  // expert weights -> bf16 transposed, shared expert in slot 8
  tcast<<<dim3(Hd / 32, Dm / 32, 8), tb, 0, stream>>>(w_fc, wfc_t, Dm, Hd);
  tcast<<<dim3(Hd / 32, Dm / 32, 8), tb, 0, stream>>>(w_gate, wgt_t, Dm, Hd);
  tcast<<<dim3(Dm / 32, Hd / 32, 8), tb, 0, stream>>>(w_proj, wpr_t, Hd, Dm);
  tcast<<<dim3(Hd / 32, Dm / 32, 1), tb, 0, stream>>>(w_sfc, wfc_t + (size_t)8 * Hd * Dm, Dm, Hd);
  tcast<<<dim3(Hd / 32, Dm / 32, 1), tb, 0, stream>>>(w_sgate, wgt_t + (size_t)8 * Hd * Dm, Dm, Hd);
  tcast<<<dim3(Dm / 32, Hd / 32, 1), tb, 0, stream>>>(w_sproj, wpr_t + (size_t)8 * Dm * Hd, Hd, Dm);

  router_kernel<<<Tt / 4, 256, 0, stream>>>(x, w_router, tok_exp, tok_w, tok_tick, counts, psum);
  make_offsets<<<1, 64, 0, stream>>>(counts, off, tile_e);
  gather_kernel<<<Tt, 256, 0, stream>>>(x, tok_exp, tok_w, tok_tick, off, rows, rwv, xg);
  gemm_fcgate<<<dim3(Hd / 64, NT_CAP), 256, 0, stream>>>(xg, wfc_t, wgt_t, tile_e, hg);
  gemm_proj<<<dim3(Dm / 64, NT_CAP), 256, 0, stream>>>(hg, wpr_t, tile_e, rows, rwv, y);
  finalize<<<1, 64, 0, stream>>>(counts, psum, y + YN);
}

// Round 4
// 1096.383 us; speedup vs baseline: 1.2812x; 1.0093x over previous
//
#include <hip/hip_runtime.h>

typedef __attribute__((ext_vector_type(4))) float floatx4;
typedef __attribute__((ext_vector_type(8))) short shortx8;

#define AS1 __attribute__((address_space(1)))
#define AS3 __attribute__((address_space(3)))

constexpr int Tt = 4096;       // tokens (2*2048)
constexpr int Dm = 1024;       // d_model
constexpr int Hd = 4096;       // hidden
constexpr int ROWS_CAP = 13312; // 104 tiles * 128: 8192 routed + pad + 4096 shared
constexpr int NT_CAP = 104;
constexpr int YN = Tt * Dm;

// ---------- helpers ----------
__device__ __forceinline__ unsigned short f2bf(float f) {
  unsigned u = __builtin_bit_cast(unsigned, f);
  u = (u + 0x7fffu + ((u >> 16) & 1u)) >> 16;  // round-to-nearest-even
  return (unsigned short)u;
}

__device__ __forceinline__ void load_lds16(const unsigned short* g, unsigned short* l) {
  __builtin_amdgcn_global_load_lds((const AS1 unsigned int*)g, (AS3 unsigned int*)l, 16, 0, 0);
}

// ---------- cast + transpose fp32 [R][C] -> bf16 [C][R], batched over z ----------
// 64x64 tile, float4 reads, ushort4 writes (HBM-bound: maximize transaction width)
__global__ void tcast(const float* __restrict__ in, unsigned short* __restrict__ out,
                      int R, int C) {
  __shared__ float t[64][68];  // 68: 16B-aligned rows, odd-ish bank stride
  size_t mat = blockIdx.z;
  const float* ip = in + mat * (size_t)R * C;
  unsigned short* op = out + mat * (size_t)R * C;
  int c0 = blockIdx.x * 64, r0 = blockIdx.y * 64;
  int tid = threadIdx.x;  // 256
  int rr = tid >> 4, cc = tid & 15;
#pragma unroll
  for (int p = 0; p < 4; p++) {
    int r = rr + p * 16;
    float4 v = *(const float4*)(ip + (size_t)(r0 + r) * C + c0 + cc * 4);
    *(float4*)&t[r][cc * 4] = v;
  }
  __syncthreads();
#pragma unroll
  for (int p = 0; p < 4; p++) {
    int c = rr + p * 16;
    ushort4 o;
    o.x = f2bf(t[cc * 4 + 0][c]);
    o.y = f2bf(t[cc * 4 + 1][c]);
    o.z = f2bf(t[cc * 4 + 2][c]);
    o.w = f2bf(t[cc * 4 + 3][c]);
    *(ushort4*)(op + (size_t)(c0 + c) * R + r0 + cc * 4) = o;
  }
}

// ---------- router: fp32 exact; 1 wave per token; ticket = atomicAdd return ----------
__global__ void router_kernel(const float* __restrict__ x, const float* __restrict__ wr,
                              int* __restrict__ tok_exp, float* __restrict__ tok_w,
                              int* __restrict__ tok_tick,
                              int* __restrict__ counts, double* __restrict__ psum) {
  int wave = threadIdx.x >> 6, lane = threadIdx.x & 63;
  int t = blockIdx.x * 4 + wave;
  const float* xp = x + (size_t)t * Dm;
  float xi[16];
#pragma unroll
  for (int j = 0; j < 16; j++) xi[j] = xp[lane + j * 64];
  float sc[8];
#pragma unroll
  for (int e = 0; e < 8; e++) {
    const float* wp = wr + e * Dm;
    float acc = 0.f;
#pragma unroll
    for (int j = 0; j < 16; j++) acc += xi[j] * wp[lane + j * 64];
#pragma unroll
    for (int s = 32; s; s >>= 1) acc += __shfl_xor(acc, s, 64);
    sc[e] = acc;
  }
  // softmax (all lanes redundantly)
  float m = sc[0];
#pragma unroll
  for (int e = 1; e < 8; e++) m = fmaxf(m, sc[e]);
  float sum = 0.f;
#pragma unroll
  for (int e = 0; e < 8; e++) { sc[e] = __expf(sc[e] - m); sum += sc[e]; }
  float inv = 1.0f / sum;
#pragma unroll
  for (int e = 0; e < 8; e++) sc[e] *= inv;
  // group scores: G=4 groups of 2; keep top-2 groups (lowest index wins ties)
  float gs[4];
#pragma unroll
  for (int g = 0; g < 4; g++) gs[g] = fmaxf(sc[2 * g], sc[2 * g + 1]);
  int g1 = -1, g2 = -1; float b1 = -1e30f, b2 = -1e30f;
#pragma unroll
  for (int g = 0; g < 4; g++) if (gs[g] > b1) { b1 = gs[g]; g1 = g; }
#pragma unroll
  for (int g = 0; g < 4; g++) if (g != g1 && gs[g] > b2) { b2 = gs[g]; g2 = g; }
  // top-2 experts among kept groups
  int e1 = -1, e2 = -1; float c1 = -1e30f, c2 = -1e30f;
#pragma unroll
  for (int e = 0; e < 8; e++) {
    int g = e >> 1; bool keep = (g == g1) || (g == g2);
    if (keep && sc[e] > c1) { c1 = sc[e]; e1 = e; }
  }
#pragma unroll
  for (int e = 0; e < 8; e++) {
    int g = e >> 1; bool keep = (g == g1) || (g == g2);
    if (keep && e != e1 && sc[e] > c2) { c2 = sc[e]; e2 = e; }
  }
  if (lane == 0) {
    int k1 = atomicAdd(&counts[e1], 1);
    int k2 = atomicAdd(&counts[e2], 1);
    tok_exp[t * 2] = e1; tok_w[t * 2] = c1; tok_tick[t * 2] = k1;
    tok_exp[t * 2 + 1] = e2; tok_w[t * 2 + 1] = c2; tok_tick[t * 2 + 1] = k2;
  }
  // psum: block-reduce in LDS, one f64 atomic per expert per block
  __shared__ float ps[4][8];
  float mysc = 0.f;
#pragma unroll
  for (int e = 0; e < 8; e++) if (e == lane) mysc = sc[e];
  if (lane < 8) ps[wave][lane] = mysc;
  __syncthreads();
  if (wave == 0 && lane < 8) {
    float s = ps[0][lane] + ps[1][lane] + ps[2][lane] + ps[3][lane];
    atomicAdd(&psum[lane], (double)s);
  }
}

// ---------- offsets + tile->expert map (serial, tiny) ----------
__global__ void make_offsets(const int* __restrict__ counts, int* __restrict__ off,
                             int* __restrict__ tile_e) {
  if (threadIdx.x == 0) {
    int o[10];
    o[0] = 0;
    for (int e = 0; e < 8; e++) o[e + 1] = o[e] + ((counts[e] + 127) & ~127);
    o[9] = o[8] + Tt;  // shared-expert segment (expert id 8), exactly Tt rows
    for (int e = 0; e < 10; e++) off[e] = o[e];
    int nt = o[9] >> 7;
    for (int i = 0; i < NT_CAP; i++) {
      int te = -1;
      if (i < nt) {
        int r = i << 7;
        for (int e = 0; e < 9; e++)
          if (r >= o[e] && r < o[e + 1]) te = e;
      }
      tile_e[i] = te;
    }
  }
}

// ---------- gather token rows (bf16) into padded per-expert segments ----------
__global__ void gather_kernel(const float* __restrict__ x, const int* __restrict__ tok_exp,
                              const float* __restrict__ tok_w, const int* __restrict__ tok_tick,
                              const int* __restrict__ off,
                              int* __restrict__ rows, float* __restrict__ rw,
                              unsigned short* __restrict__ xg) {
  int t = blockIdx.x;
  int tid = threadIdx.x;
  __shared__ int spos[3];
  if (tid < 2) {
    int e = tok_exp[t * 2 + tid];
    int p = off[e] + tok_tick[t * 2 + tid];
    spos[tid] = p; rows[p] = t; rw[p] = tok_w[t * 2 + tid];
  } else if (tid == 2) {
    int p = off[8] + t;
    spos[2] = p; rows[p] = t; rw[p] = 1.0f;
  }
  __syncthreads();
  float4 v = ((const float4*)(x + (size_t)t * Dm))[tid];  // 256 threads * float4 = 1024
  ushort4 b;
  b.x = f2bf(v.x); b.y = f2bf(v.y); b.z = f2bf(v.z); b.w = f2bf(v.w);
#pragma unroll
  for (int k = 0; k < 3; k++)
    ((ushort4*)(xg + (size_t)spos[k] * Dm))[tid] = b;
}

// ---------- GEMM1: h = (Xg @ Wfc) * silu(Xg @ Wgate), bf16 out ----------
// 128x64 tile, BK=64, 4 waves (2x2, wave tile 64x32 per matrix), mfma 16x16x32.
// Grid: x = row-tile (fast) so consecutive blocks share n0 -> B window ~2.4MB (L2);
// launch_bounds(256,3) -> 3 blocks/CU. LDS XOR-swizzled -> ~zero bank conflicts.
__global__ __launch_bounds__(256, 3) void gemm_fcgate(
    const unsigned short* __restrict__ xg,   // [ROWS_CAP][Dm]
    const unsigned short* __restrict__ wfc,  // [9][Hd][Dm]  (row=n, col=k)
    const unsigned short* __restrict__ wgt,  // [9][Hd][Dm]
    const int* __restrict__ tile_e,
    unsigned short* __restrict__ hg)         // [ROWS_CAP][Hd]
{
  int rt = blockIdx.x;
  int e = tile_e[rt];
  if (e < 0) return;
  int n0 = blockIdx.y * 64;
  __shared__ __align__(16) unsigned short lds[128 * 64 + 2 * 64 * 64];  // 32KB
  unsigned short* a_s = lds;
  unsigned short* bf_s = lds + 128 * 64;
  unsigned short* bg_s = lds + 128 * 64 + 64 * 64;
  int tid = threadIdx.x;
  int wave = tid >> 6, lane = tid & 63;
  int quad = lane >> 4, l15 = lane & 15;
  int sx = l15 & 7;  // fragment-read XOR key (row & 7)
  const unsigned short* Ab = xg + (size_t)rt * 128 * Dm;
  const unsigned short* Bf = wfc + (size_t)e * Hd * Dm + (size_t)n0 * Dm;
  const unsigned short* Bg = wgt + (size_t)e * Hd * Dm + (size_t)n0 * Dm;

  floatx4 zero4 = {0.f, 0.f, 0.f, 0.f};
  floatx4 accf[4][2], accg[4][2];
#pragma unroll
  for (int i = 0; i < 4; i++)
#pragma unroll
    for (int j = 0; j < 2; j++) { accf[i][j] = zero4; accg[i][j] = zero4; }

  int wm = (wave & 1) * 64, wn = (wave >> 1) * 32;

  for (int k0 = 0; k0 < Dm; k0 += 64) {
#pragma unroll
    for (int i = 0; i < 4; i++) {  // A: 128x64 = 16 wave-chunks, 4 per wave
      int c = (wave * 4 + i) * 64 + lane;
      int row = c >> 3;
      int col = (((c & 7) ^ (row & 7)) << 3);
      load_lds16(Ab + (size_t)row * Dm + k0 + col, a_s + (wave * 4 + i) * 512);
    }
#pragma unroll
    for (int i = 0; i < 2; i++) {  // Bf/Bg: 64x64 = 8 wave-chunks, 2 per wave
      int c = (wave * 2 + i) * 64 + lane;
      int row = c >> 3;
      int col = (((c & 7) ^ (row & 7)) << 3);
      load_lds16(Bf + (size_t)row * Dm + k0 + col, bf_s + (wave * 2 + i) * 512);
      load_lds16(Bg + (size_t)row * Dm + k0 + col, bg_s + (wave * 2 + i) * 512);
    }
    __syncthreads();
#pragma unroll
    for (int kk = 0; kk < 64; kk += 32) {
      shortx8 af[4], bff[2], bgf[2];
      int cl = (kk >> 3) + quad;
      int co = ((cl ^ sx) << 3);
#pragma unroll
      for (int mi = 0; mi < 4; mi++)
        af[mi] = *(const shortx8*)(a_s + (wm + mi * 16 + l15) * 64 + co);
#pragma unroll
      for (int ni = 0; ni < 2; ni++) {
        bff[ni] = *(const shortx8*)(bf_s + (wn + ni * 16 + l15) * 64 + co);
        bgf[ni] = *(const shortx8*)(bg_s + (wn + ni * 16 + l15) * 64 + co);
      }
#pragma unroll
      for (int mi = 0; mi < 4; mi++)
#pragma unroll
        for (int ni = 0; ni < 2; ni++) {
          accf[mi][ni] = __builtin_amdgcn_mfma_f32_16x16x32_bf16(af[mi], bff[ni], accf[mi][ni], 0, 0, 0);
          accg[mi][ni] = __builtin_amdgcn_mfma_f32_16x16x32_bf16(af[mi], bgf[ni], accg[mi][ni], 0, 0, 0);
        }
    }
    __syncthreads();
  }
  // epilogue: silu-combine, transpose via LDS (stride 72: 16B-aligned)
  unsigned short* h_s = lds;  // 128*72*2B = 18KB
#pragma unroll
  for (int mi = 0; mi < 4; mi++)
#pragma unroll
    for (int ni = 0; ni < 2; ni++)
#pragma unroll
      for (int r = 0; r < 4; r++) {
        float fc = accf[mi][ni][r], gt = accg[mi][ni][r];
        float h = fc * (gt / (1.0f + __expf(-gt)));
        int m = wm + mi * 16 + quad * 4 + r;
        int n = wn + ni * 16 + l15;
        h_s[m * 72 + n] = f2bf(h);
      }
  __syncthreads();
#pragma unroll
  for (int i = 0; i < 4; i++) {
    int c = i * 256 + tid;          // 1024 chunks of 8 elems
    int row = c >> 3, col = (c & 7) * 8;
    *(shortx8*)(hg + (size_t)(rt * 128 + row) * Hd + n0 + col) =
        *(const shortx8*)(h_s + row * 72 + col);
  }
}

// ---------- GEMM2: y[t] += rw * (h @ Wproj)   (shared expert has rw=1) ----------
// 128x64 tile, wave tile 64x32: acc = 32 AGPRs -> high occupancy.
__global__ __launch_bounds__(256, 3) void gemm_proj(
    const unsigned short* __restrict__ hg,   // [ROWS_CAP][Hd]
    const unsigned short* __restrict__ wpr,  // [9][Dm][Hd] (row=n, col=k)
    const int* __restrict__ tile_e,
    const int* __restrict__ rows,
    const float* __restrict__ rw,
    float* __restrict__ y)
{
  int rt = blockIdx.x;
  int e = tile_e[rt];
  if (e < 0) return;
  int n0 = blockIdx.y * 64;
  __shared__ __align__(16) unsigned short lds[128 * 64 + 64 * 64];  // 24KB
  unsigned short* a_s = lds;
  unsigned short* b_s = lds + 128 * 64;
  int tid = threadIdx.x;
  int wave = tid >> 6, lane = tid & 63;
  int quad = lane >> 4, l15 = lane & 15;
  int sx = l15 & 7;
  const unsigned short* Ab = hg + (size_t)rt * 128 * Hd;
  const unsigned short* Bb = wpr + (size_t)e * Dm * Hd + (size_t)n0 * Hd;

  floatx4 zero4 = {0.f, 0.f, 0.f, 0.f};
  floatx4 acc[4][2];
#pragma unroll
  for (int i = 0; i < 4; i++)
#pragma unroll
    for (int j = 0; j < 2; j++) acc[i][j] = zero4;

  int wm = (wave & 1) * 64, wn = (wave >> 1) * 32;

  for (int k0 = 0; k0 < Hd; k0 += 64) {
#pragma unroll
    for (int i = 0; i < 4; i++) {
      int c = (wave * 4 + i) * 64 + lane;
      int row = c >> 3;
      int col = (((c & 7) ^ (row & 7)) << 3);
      load_lds16(Ab + (size_t)row * Hd + k0 + col, a_s + (wave * 4 + i) * 512);
    }
#pragma unroll
    for (int i = 0; i < 2; i++) {
      int c = (wave * 2 + i) * 64 + lane;
      int row = c >> 3;
      int col = (((c & 7) ^ (row & 7)) << 3);
      load_lds16(Bb + (size_t)row * Hd + k0 + col, b_s + (wave * 2 + i) * 512);
    }
    __syncthreads();
#pragma unroll
    for (int kk = 0; kk < 64; kk += 32) {
      shortx8 af[4], bf[2];
      int cl = (kk >> 3) + quad;
      int co = ((cl ^ sx) << 3);
#pragma unroll
      for (int mi = 0; mi < 4; mi++)
        af[mi] = *(const shortx8*)(a_s + (wm + mi * 16 + l15) * 64 + co);
#pragma unroll
      for (int ni = 0; ni < 2; ni++)
        bf[ni] = *(const shortx8*)(b_s + (wn + ni * 16 + l15) * 64 + co);
#pragma unroll
      for (int mi = 0; mi < 4; mi++)
#pragma unroll
        for (int ni = 0; ni < 2; ni++)
          acc[mi][ni] = __builtin_amdgcn_mfma_f32_16x16x32_bf16(af[mi], bf[ni], acc[mi][ni], 0, 0, 0);
    }
    __syncthreads();
  }
  // epilogue: weighted atomic scatter into y
  int grbase = rt * 128;
#pragma unroll
  for (int mi = 0; mi < 4; mi++) {
#pragma unroll
    for (int r = 0; r < 4; r++) {
      int gr = grbase + wm + mi * 16 + quad * 4 + r;
      int t = rows[gr];
      float w = rw[gr];
      if (w != 0.0f) {
#pragma unroll
        for (int ni = 0; ni < 2; ni++) {
          int col = n0 + wn + ni * 16 + l15;
          unsafeAtomicAdd(&y[(size_t)t * Dm + col], w * acc[mi][ni][r]);
        }
      }
    }
  }
}

// ---------- finalize: lb_loss + counts into output tail ----------
__global__ void finalize(const int* __restrict__ counts, const double* __restrict__ psum,
                         float* __restrict__ out_tail) {
  int tid = threadIdx.x;
  if (tid == 0) {
    double acc = 0.0;
    for (int e = 0; e < 8; e++) {
      double f = counts[e] / (double)(Tt * 2);
      double p = psum[e] / (double)Tt;
      acc += f * p;
    }
    out_tail[0] = (float)(8.0 * acc - 1.0);
  }
  if (tid < 8) out_tail[1 + tid] = (float)counts[tid];
}

// ---------- launch ----------
extern "C" void kernel_launch(void* const* d_in, const int* in_sizes, int n_in,
                              void* d_out, int out_size, void* d_ws, size_t ws_size,
                              hipStream_t stream) {
  const float* x        = (const float*)d_in[0];
  const float* w_router = (const float*)d_in[1];
  const float* w_fc     = (const float*)d_in[2];
  const float* w_gate   = (const float*)d_in[3];
  const float* w_proj   = (const float*)d_in[4];
  const float* w_sfc    = (const float*)d_in[5];
  const float* w_sgate  = (const float*)d_in[6];
  const float* w_sproj  = (const float*)d_in[7];
  float* y = (float*)d_out;

  char* p = (char*)d_ws;
  auto alloc = [&](size_t bytes) {
    char* r = p;
    p += (bytes + 255) & ~(size_t)255;
    return r;
  };
  unsigned short* wfc_t = (unsigned short*)alloc((size_t)9 * Hd * Dm * 2);
  unsigned short* wgt_t = (unsigned short*)alloc((size_t)9 * Hd * Dm * 2);
  unsigned short* wpr_t = (unsigned short*)alloc((size_t)9 * Dm * Hd * 2);
  unsigned short* xg    = (unsigned short*)alloc((size_t)ROWS_CAP * Dm * 2);
  unsigned short* hg    = (unsigned short*)alloc((size_t)ROWS_CAP * Hd * 2);
  char* zbase = p;  // start of zero-initialized block
  int* rows    = (int*)alloc(ROWS_CAP * 4);
  float* rwv   = (float*)alloc(ROWS_CAP * 4);
  int* counts  = (int*)alloc(64);
  double* psum = (double*)alloc(64);
  size_t zbytes = (size_t)(p - zbase);
  int* tok_exp = (int*)alloc(Tt * 2 * 4);
  float* tok_w = (float*)alloc(Tt * 2 * 4);
  int* tok_tick= (int*)alloc(Tt * 2 * 4);
  int* off     = (int*)alloc(64);
  int* tile_e  = (int*)alloc(NT_CAP * 4);

  hipMemsetAsync(d_out, 0, (size_t)out_size * 4, stream);
  hipMemsetAsync(xg, 0, (size_t)ROWS_CAP * Dm * 2, stream);
  hipMemsetAsync(zbase, 0, zbytes, stream);

  dim3 tb(256);
  // expert weights -> bf16 transposed, shared expert in slot 8
  tcast<<<dim3(Hd / 64, Dm / 64, 8), tb, 0, stream>>>(w_fc, wfc_t, Dm, Hd);
  tcast<<<dim3(Hd / 64, Dm / 64, 8), tb, 0, stream>>>(w_gate, wgt_t, Dm, Hd);
  tcast<<<dim3(Dm / 64, Hd / 64, 8), tb, 0, stream>>>(w_proj, wpr_t, Hd, Dm);
  tcast<<<dim3(Hd / 64, Dm / 64, 1), tb, 0, stream>>>(w_sfc, wfc_t + (size_t)8 * Hd * Dm, Dm, Hd);
  tcast<<<dim3(Hd / 64, Dm / 64, 1), tb, 0, stream>>>(w_sgate, wgt_t + (size_t)8 * Hd * Dm, Dm, Hd);
  tcast<<<dim3(Dm / 64, Hd / 64, 1), tb, 0, stream>>>(w_sproj, wpr_t + (size_t)8 * Dm * Hd, Hd, Dm);

  router_kernel<<<Tt / 4, 256, 0, stream>>>(x, w_router, tok_exp, tok_w, tok_tick, counts, psum);
  make_offsets<<<1, 64, 0, stream>>>(counts, off, tile_e);
  gather_kernel<<<Tt, 256, 0, stream>>>(x, tok_exp, tok_w, tok_tick, off, rows, rwv, xg);
  gemm_fcgate<<<dim3(NT_CAP, Hd / 64), 256, 0, stream>>>(xg, wfc_t, wgt_t, tile_e, hg);
  gemm_proj<<<dim3(NT_CAP, Dm / 64), 256, 0, stream>>>(hg, wpr_t, tile_e, rows, rwv, y);
  finalize<<<1, 64, 0, stream>>>(counts, psum, y + YN);
}